// Round 9
// baseline (233.062 us; speedup 1.0000x reference)
//
#include <hip/hip_runtime.h>
#include <math.h>

#define Mq 12288          // B*T
#define Nq 768            // C (per-matrix output width)
#define Kq 768            // C (reduce dim)
#define Tq 768
#define Bq 16
#define Cq 768
#define BK 64             // K-tile (bf16) = 128 B = 8 x 16B chunks
#define NKT (Kq / BK)     // 12 K-tiles
#define BM 128            // gemm2 (m97) tile

typedef __bf16 bf16x8 __attribute__((ext_vector_type(8)));
typedef __bf16 bf16x4 __attribute__((ext_vector_type(4)));
typedef __bf16 bf16x2 __attribute__((ext_vector_type(2)));
typedef float  floatx4 __attribute__((ext_vector_type(4)));

// async 16B/lane global->LDS (LDS operand is wave-uniform base; HW adds lane*16)
#define GLD_LDS16(g, l) __builtin_amdgcn_global_load_lds(                      \
    (const __attribute__((address_space(1))) unsigned int*)(g),                \
    (__attribute__((address_space(3))) unsigned int*)(l), 16, 0, 0)

// ---------------------------------------------------------------------------
// Fused prep (R8, unchanged): 8 ch/thread, 16B stores, NO swizzle (R7 lesson).
// ---------------------------------------------------------------------------
__global__ __launch_bounds__(256)
void prep_kernel(const float* __restrict__ x,
                 const float* __restrict__ mk, const float* __restrict__ mv,
                 const float* __restrict__ mr,
                 const float* __restrict__ Wk, const float* __restrict__ Wv,
                 const float* __restrict__ Wr, const float* __restrict__ Wo,
                 __bf16* __restrict__ xk, __bf16* __restrict__ xv,
                 __bf16* __restrict__ xr, __bf16* __restrict__ wp)
{
    const int bid = blockIdx.x;
    if (bid < 4608) {
        const int i  = bid * 256 + threadIdx.x;
        const int c8 = i % (Cq / 8);
        const int m  = i / (Cq / 8);
        const int t  = m % Tq;
        const int c0 = c8 * 8;

        const float4 xa = *(const float4*)(x + (size_t)m * Cq + c0);
        const float4 xb = *(const float4*)(x + (size_t)m * Cq + c0 + 4);
        float4 pa = make_float4(0.f, 0.f, 0.f, 0.f);
        float4 pb = make_float4(0.f, 0.f, 0.f, 0.f);
        if (t > 0) {
            pa = *(const float4*)(x + (size_t)(m - 1) * Cq + c0);
            pb = *(const float4*)(x + (size_t)(m - 1) * Cq + c0 + 4);
        }
        const float xc[8] = { xa.x, xa.y, xa.z, xa.w, xb.x, xb.y, xb.z, xb.w };
        const float xp[8] = { pa.x, pa.y, pa.z, pa.w, pb.x, pb.y, pb.z, pb.w };

        const size_t o = (size_t)m * Cq + c0;
        {
            const float4 ma = *(const float4*)(mk + c0);
            const float4 mb = *(const float4*)(mk + c0 + 4);
            const float mm[8] = { ma.x, ma.y, ma.z, ma.w, mb.x, mb.y, mb.z, mb.w };
            bf16x8 ov;
#pragma unroll
            for (int j = 0; j < 8; ++j)
                ov[j] = (__bf16)fmaf(mm[j], xc[j] - xp[j], xp[j]);
            *(bf16x8*)(xk + o) = ov;
        }
        {
            const float4 ma = *(const float4*)(mv + c0);
            const float4 mb = *(const float4*)(mv + c0 + 4);
            const float mm[8] = { ma.x, ma.y, ma.z, ma.w, mb.x, mb.y, mb.z, mb.w };
            bf16x8 ov;
#pragma unroll
            for (int j = 0; j < 8; ++j)
                ov[j] = (__bf16)fmaf(mm[j], xc[j] - xp[j], xp[j]);
            *(bf16x8*)(xv + o) = ov;
        }
        {
            const float4 ma = *(const float4*)(mr + c0);
            const float4 mb = *(const float4*)(mr + c0 + 4);
            const float mm[8] = { ma.x, ma.y, ma.z, ma.w, mb.x, mb.y, mb.z, mb.w };
            bf16x8 ov;
#pragma unroll
            for (int j = 0; j < 8; ++j)
                ov[j] = (__bf16)fmaf(mm[j], xc[j] - xp[j], xp[j]);
            *(bf16x8*)(xr + o) = ov;
        }
    } else {
        const int i   = (bid - 4608) * 256 + threadIdx.x;
        const int a   = i / 73728;
        const int off = (i - a * 73728) * 8;
        const float* s = (a == 0) ? Wk : (a == 1) ? Wv : (a == 2) ? Wr : Wo;
        const float4 va = *(const float4*)(s + off);
        const float4 vb = *(const float4*)(s + off + 4);
        bf16x8 r = { (__bf16)va.x, (__bf16)va.y, (__bf16)va.z, (__bf16)va.w,
                     (__bf16)vb.x, (__bf16)vb.y, (__bf16)vb.z, (__bf16)vb.w };
        *(bf16x8*)(wp + (size_t)a * 589824 + off) = r;
    }
}

// ---------------------------------------------------------------------------
// 8-phase-style 256x256 GEMM for k|v|r (T3+T4+T5 port, stripe-safe schedule).
// 512 thr = 8 waves (wm=tok-half 0..1, wn=ch-quarter 0..3); per-wave output
// 128 tok x 64 ch; acc[4][8] floatx4 = 128 VGPR.  LDS = 2 K-tile buffers x
// (W 256x64 + X 256x64) = 128 KiB.  Per K-tile: 4 phases (one C-quadrant
// qc,qt each: 12 ds_read_b128 + one half-tile stage (2 gld_lds/wave) +
// barrier + lgkmcnt(0) + setprio MFMA x16 + barrier), then ONE counted
// vmcnt(4) + barrier.  NEVER vmcnt(0) in the main loop.
// Safety ledger:
//  - stripes: X-qt0 rows{0-63,128-191} last read ph2 -> staged ph3;
//    W-qc0 rows{0-31,64-95,128-159,192-223} last read ph3 -> staged ph4;
//    X-qt1/W-qc1 of dbuf d free after ph4 -> staged NEXT iter ph1/ph2
//    (they then target dbuf d^1, not read by that iter).  All stage
//    destinations are read-complete across all waves (closing barriers).
//  - RAW: vmcnt(4) at end of iter u retires X0,W0(u+1) [staged iter u-1
//    ph3/4] and X1,W1(u+1) [staged iter u ph1/2], leaving only X0,W0(u+2)
//    in flight -> tile u+1 fully landed before iter u+1 reads it.
//  - iter 10: vmcnt(0) (tile 11's late halves have no younger loads to
//    count against); iter 11: pure compute.  Prologue: tiles 0,1 + vmcnt(0).
// Grid 432 = 8 XCDs x 54 (bijective swizzle), 9 n-strips (3 per matrix).
// ---------------------------------------------------------------------------
__device__ __forceinline__ void stageW(const __bf16* Wb, __bf16* ldsW,
                                       int kt, int qc, int wv, int lane)
{
    const int sc = (lane & 7) ^ (lane >> 3);
#pragma unroll
    for (int g = 0; g < 2; ++g) {
        const int gi = wv * 2 + g;                       // 0..15
        const int r0 = (gi >> 2) * 64 + qc * 32 + (gi & 3) * 8;
        GLD_LDS16(Wb + (size_t)(r0 + (lane >> 3)) * Kq + kt * 64 + sc * 8,
                  ldsW + r0 * 64);
    }
}
__device__ __forceinline__ void stageX(const __bf16* Xb, __bf16* ldsX,
                                       int kt, int qt, int wv, int lane)
{
    const int sc = (lane & 7) ^ (lane >> 3);
#pragma unroll
    for (int g = 0; g < 2; ++g) {
        const int gi = wv * 2 + g;                       // 0..15
        const int r0 = (gi >> 3) * 128 + qt * 64 + (gi & 7) * 8;
        GLD_LDS16(Xb + (size_t)(r0 + (lane >> 3)) * Kq + kt * 64 + sc * 8,
                  ldsX + r0 * 64);
    }
}

#define PHASE(QC, QT, STAGE_STMT) do {                                         \
    bf16x8 wF[2][2], xF[4][2];                                                 \
    _Pragma("unroll")                                                          \
    for (int ii = 0; ii < 2; ++ii) {                                           \
        const int r = wn * 64 + QC * 32 + ii * 16 + (lane & 15);               \
        _Pragma("unroll")                                                      \
        for (int kk = 0; kk < 2; ++kk)                                         \
            wF[ii][kk] = *(const bf16x8*)(ldsW + r * 64 +                      \
                             ((((kk) << 2) | lk) ^ (r & 7)) * 8);              \
    }                                                                          \
    _Pragma("unroll")                                                          \
    for (int jj = 0; jj < 4; ++jj) {                                           \
        const int r = wm * 128 + QT * 64 + jj * 16 + (lane & 15);              \
        _Pragma("unroll")                                                      \
        for (int kk = 0; kk < 2; ++kk)                                         \
            xF[jj][kk] = *(const bf16x8*)(ldsX + r * 64 +                      \
                             ((((kk) << 2) | lk) ^ (r & 7)) * 8);              \
    }                                                                          \
    STAGE_STMT;                                                                \
    __builtin_amdgcn_s_barrier();                                              \
    asm volatile("s_waitcnt lgkmcnt(0)" ::: "memory");                         \
    __builtin_amdgcn_s_setprio(1);                                             \
    _Pragma("unroll")                                                          \
    for (int ii = 0; ii < 2; ++ii)                                             \
        _Pragma("unroll")                                                      \
        for (int jj = 0; jj < 4; ++jj)                                         \
            _Pragma("unroll")                                                  \
            for (int kk = 0; kk < 2; ++kk)                                     \
                acc[QC * 2 + ii][QT * 4 + jj] =                                \
                    __builtin_amdgcn_mfma_f32_16x16x32_bf16(                   \
                        wF[ii][kk], xF[jj][kk],                                \
                        acc[QC * 2 + ii][QT * 4 + jj], 0, 0, 0);               \
    __builtin_amdgcn_s_setprio(0);                                             \
    __builtin_amdgcn_s_barrier();                                              \
} while (0)

__global__ __launch_bounds__(512, 2)
void gemm_kvr8(const __bf16* __restrict__ A0, const __bf16* __restrict__ A1,
               const __bf16* __restrict__ A2,
               const __bf16* __restrict__ W,
               __bf16* __restrict__ OUTb)
{
    __shared__ __bf16 LDS[65536];     // 128 KiB: 2 x (W 16384 + X 16384)

    // ---- swizzle: 432 = 8 XCDs x (9 strips x 6 m-tiles), strip-fastest
    const int bid  = blockIdx.x;
    const int xcd  = bid & 7;
    const int j_   = bid >> 3;        // 0..53
    const int nt   = j_ % 9;          // n-strip (matid*3 + slice)
    const int mt   = xcd * 6 + j_ / 9;

    const int tid  = threadIdx.x;
    const int wv   = tid >> 6;        // 0..7
    const int lane = tid & 63;
    const int wm   = wv >> 2;         // token half (128)
    const int wn   = wv & 3;          // channel quarter (64)
    const int lk   = lane >> 4;

    const int m0    = mt * 256;
    const int matid = nt / 3;
    const int nc0   = (nt % 3) * 256; // column base within the matrix

    const __bf16* Xb = (matid == 0) ? A0 : (matid == 1) ? A1 : A2;
    const __bf16* Wb = W + (size_t)(matid * 768 + nc0) * Kq;
    Xb += (size_t)m0 * Kq;

    floatx4 acc[4][8];
#pragma unroll
    for (int i = 0; i < 4; ++i)
#pragma unroll
        for (int j = 0; j < 8; ++j) acc[i][j] = (floatx4){0.f, 0.f, 0.f, 0.f};

    // ---- prologue: stage K-tiles 0,1 fully; drain; barrier
#pragma unroll
    for (int t = 0; t < 2; ++t) {
        __bf16* lw = LDS + t * 32768;
        __bf16* lx = lw + 16384;
        stageX(Xb, lx, t, 0, wv, lane);
        stageX(Xb, lx, t, 1, wv, lane);
        stageW(Wb, lw, t, 0, wv, lane);
        stageW(Wb, lw, t, 1, wv, lane);
    }
    asm volatile("s_waitcnt vmcnt(0)" ::: "memory");
    __builtin_amdgcn_s_barrier();

    // ---- main loop: iters 0..10 (compute tile u, stage ahead)
    for (int u = 0; u < NKT - 1; ++u) {
        const __bf16* ldsW = LDS + (u & 1) * 32768;
        const __bf16* ldsX = ldsW + 16384;
        __bf16* sN = LDS + ((u + 1) & 1) * 32768;   // dbuf of tile u+1
        __bf16* sC = LDS + (u & 1) * 32768;         // dbuf of tile u+2

        PHASE(0, 0, { if (u >= 1)       stageX(Xb, sN + 16384, u + 1, 1, wv, lane); });
        PHASE(1, 0, { if (u >= 1)       stageW(Wb, sN,         u + 1, 1, wv, lane); });
        PHASE(0, 1, { if (u < NKT - 2)  stageX(Xb, sC + 16384, u + 2, 0, wv, lane); });
        PHASE(1, 1, { if (u < NKT - 2)  stageW(Wb, sC,         u + 2, 0, wv, lane); });

        if (u < NKT - 2) asm volatile("s_waitcnt vmcnt(4)" ::: "memory");
        else             asm volatile("s_waitcnt vmcnt(0)" ::: "memory");
        __builtin_amdgcn_s_barrier();
    }
    {   // ---- final iteration u = NKT-1: pure compute
        const __bf16* ldsW = LDS + ((NKT - 1) & 1) * 32768;
        const __bf16* ldsX = ldsW + 16384;
        PHASE(0, 0, {});
        PHASE(1, 0, {});
        PHASE(0, 1, {});
        PHASE(1, 1, {});
    }

    // ---- epilogue: fused activation + store (same fragment map as m97)
#pragma unroll
    for (int j = 0; j < 8; ++j) {
        const int tok = m0 + wm * 128 + j * 16 + (lane & 15);
#pragma unroll
        for (int i = 0; i < 4; ++i) {
            const int ch = nc0 + wn * 64 + i * 16 + (lane >> 4) * 4;
            float v0 = acc[i][j][0], v1 = acc[i][j][1];
            float v2 = acc[i][j][2], v3 = acc[i][j][3];
            if (matid == 0) {
                v0 = expf(fminf(v0, 60.f)); v1 = expf(fminf(v1, 60.f));
                v2 = expf(fminf(v2, 60.f)); v3 = expf(fminf(v3, 60.f));
            } else if (matid == 2) {
                v0 = 1.f / (1.f + expf(-v0)); v1 = 1.f / (1.f + expf(-v1));
                v2 = 1.f / (1.f + expf(-v2)); v3 = 1.f / (1.f + expf(-v3));
            }
            bf16x4 o = { (__bf16)v0, (__bf16)v1, (__bf16)v2, (__bf16)v3 };
            *(bf16x4*)(OUTb + (size_t)matid * Mq * Nq +
                       (size_t)tok * Nq + ch) = o;
        }
    }
}

// ---------------------------------------------------------------------------
// m97-structure 128x128 GEMM (proven) — used for the final Wo GEMM only.
// ---------------------------------------------------------------------------
__global__ __launch_bounds__(256, 3)
void mfma_gemm_o(const __bf16* __restrict__ A0, const __bf16* __restrict__ W,
                 float* __restrict__ OUTf)
{
    __shared__ __bf16 As[BM * BK];
    __shared__ __bf16 Bs[128 * BK];

    const int STRIPS = 6;
    const int i_    = blockIdx.x;
    const int xcd   = i_ & 7;
    const int j_    = i_ >> 3;
    const int strip = j_ % STRIPS;
    const int mt    = xcd * 12 + j_ / STRIPS;

    const int tid   = threadIdx.x;
    const int wave  = tid >> 6;
    const int lane  = tid & 63;
    const int m0    = mt * BM;
    const int n0    = strip * 128;

    const int r8 = lane >> 3;
    const int sc = (lane & 7) ^ r8;
    const __bf16* gA[4];  __bf16* lA[4];
    const __bf16* gB[4];  __bf16* lB[4];
#pragma unroll
    for (int i = 0; i < 4; ++i) {
        const int row = (wave * 4 + i) * 8 + r8;
        gA[i] = A0 + (size_t)(m0 + row) * Kq + sc * 8;
        lA[i] = As + (wave * 4 + i) * 512;
        gB[i] = W + (size_t)(n0 + row) * Kq + sc * 8;
        lB[i] = Bs + (wave * 4 + i) * 512;
    }

    const int wm   = wave & 1;
    const int wn   = wave >> 1;
    const int xRow = wm * 64 + (lane & 15);
    const int wRow = wn * 64 + (lane & 15);
    const int lk   = lane >> 4;

    floatx4 acc[4][4];
#pragma unroll
    for (int i = 0; i < 4; ++i)
#pragma unroll
        for (int j = 0; j < 4; ++j) acc[i][j] = (floatx4){0.f, 0.f, 0.f, 0.f};

    for (int kt = 0; kt < NKT; ++kt) {
#pragma unroll
        for (int i = 0; i < 4; ++i) { GLD_LDS16(gA[i], lA[i]); gA[i] += BK; }
#pragma unroll
        for (int i = 0; i < 4; ++i) { GLD_LDS16(gB[i], lB[i]); gB[i] += BK; }
        __syncthreads();

#pragma unroll
        for (int kk = 0; kk < 2; ++kk) {
            bf16x8 wF[4], xF[4];
#pragma unroll
            for (int i = 0; i < 4; ++i) {
                const int r = wRow + i * 16;
                wF[i] = *(const bf16x8*)(Bs + r * BK +
                                         (((kk << 2) | lk) ^ (r & 7)) * 8);
            }
#pragma unroll
            for (int j = 0; j < 4; ++j) {
                const int r = xRow + j * 16;
                xF[j] = *(const bf16x8*)(As + r * BK +
                                         (((kk << 2) | lk) ^ (r & 7)) * 8);
            }
#pragma unroll
            for (int i = 0; i < 4; ++i)
#pragma unroll
                for (int j = 0; j < 4; ++j)
                    acc[i][j] = __builtin_amdgcn_mfma_f32_16x16x32_bf16(
                        wF[i], xF[j], acc[i][j], 0, 0, 0);
        }
        __syncthreads();
    }

#pragma unroll
    for (int j = 0; j < 4; ++j) {
        const int tok = m0 + wm * 64 + j * 16 + (lane & 15);
#pragma unroll
        for (int i = 0; i < 4; ++i) {
            const int ch = n0 + wn * 64 + i * 16 + (lane >> 4) * 4;
            floatx4 o = acc[i][j];
            *(floatx4*)(OUTf + (size_t)tok * Nq + ch) = o;
        }
    }
}

// ---------------------------------------------------------------------------
// Segmented RWKV scan (R5 champion, untouched).
// ---------------------------------------------------------------------------
#define SEG 16
#define SLEN (Tq / SEG)   // 48

__global__ __launch_bounds__(1024)
void scan_kernel(const __bf16* __restrict__ kb, const __bf16* __restrict__ vb,
                 __bf16* rb,
                 const float* __restrict__ td, const float* __restrict__ tf)
{
    __shared__ float2 aS[SEG][64];
    __shared__ float2 bS[SEG][64];

    const int cx  = threadIdx.x;
    const int seg = threadIdx.y;
    const int c0  = blockIdx.x * 128 + cx * 2;
    const int b   = blockIdx.y;

    const float d0 = expf(td[c0]),     d1 = expf(td[c0 + 1]);
    const float w0 = expf(-d0),        w1 = expf(-d1);
    const float u0 = expf(tf[c0]),     u1 = expf(tf[c0 + 1]);

    const size_t base = ((size_t)b * Tq + seg * SLEN) * Cq + c0;

    float a0 = 0.f, a1 = 0.f, s0 = 0.f, s1 = 0.f;
#pragma unroll 4
    for (int t = 0; t < SLEN; ++t) {
        const size_t idx = base + (size_t)t * Cq;
        const bf16x2 k2 = *(const bf16x2*)(kb + idx);
        const bf16x2 v2 = *(const bf16x2*)(vb + idx);
        const float k0 = (float)k2[0], k1 = (float)k2[1];
        a0 = fmaf(w0, a0, k0 * (float)v2[0]);
        a1 = fmaf(w1, a1, k1 * (float)v2[1]);
        s0 = fmaf(w0, s0, k0);
        s1 = fmaf(w1, s1, k1);
    }
    aS[seg][cx] = make_float2(a0, a1);
    bS[seg][cx] = make_float2(s0, s1);
    __syncthreads();

    if (seg == 0) {
        const float W0 = expf(-d0 * (float)SLEN);
        const float W1 = expf(-d1 * (float)SLEN);
        float ia0 = 0.f, ia1 = 0.f, ib0 = 0.f, ib1 = 0.f;
#pragma unroll
        for (int s = 0; s < SEG; ++s) {
            const float2 ta = aS[s][cx];
            const float2 tb = bS[s][cx];
            aS[s][cx] = make_float2(ia0, ia1);
            bS[s][cx] = make_float2(ib0, ib1);
            ia0 = fmaf(W0, ia0, ta.x);  ia1 = fmaf(W1, ia1, ta.y);
            ib0 = fmaf(W0, ib0, tb.x);  ib1 = fmaf(W1, ib1, tb.y);
        }
    }
    __syncthreads();

    const float2 ain = aS[seg][cx];
    const float2 bin = bS[seg][cx];
    a0 = ain.x; a1 = ain.y; s0 = bin.x; s1 = bin.y;
#pragma unroll 2
    for (int t = 0; t < SLEN; ++t) {
        const size_t idx = base + (size_t)t * Cq;
        const bf16x2 k2 = *(const bf16x2*)(kb + idx);
        const bf16x2 v2 = *(const bf16x2*)(vb + idx);
        const bf16x2 r2 = *(const bf16x2*)(rb + idx);
        const float k0 = (float)k2[0], k1 = (float)k2[1];
        const float kv0 = k0 * (float)v2[0], kv1 = k1 * (float)v2[1];
        const float n0 = fmaf(u0, kv0, a0), n1 = fmaf(u1, kv1, a1);
        const float e0 = fmaf(u0, k0, s0) + 1e-8f;
        const float e1 = fmaf(u1, k1, s1) + 1e-8f;
        const float i0 = __builtin_amdgcn_rcpf(e0);
        const float i1 = __builtin_amdgcn_rcpf(e1);
        bf16x2 o = { (__bf16)((float)r2[0] * n0 * i0),
                     (__bf16)((float)r2[1] * n1 * i1) };
        *(bf16x2*)(rb + idx) = o;
        a0 = fmaf(w0, a0, kv0);  a1 = fmaf(w1, a1, kv1);
        s0 = fmaf(w0, s0, k0);   s1 = fmaf(w1, s1, k1);
    }
}

extern "C" void kernel_launch(void* const* d_in, const int* in_sizes, int n_in,
                              void* d_out, int out_size, void* d_ws, size_t ws_size,
                              hipStream_t stream)
{
    const float* x  = (const float*)d_in[0];
    const float* td = (const float*)d_in[1];
    const float* tf = (const float*)d_in[2];
    const float* mk = (const float*)d_in[3];
    const float* mv = (const float*)d_in[4];
    const float* mr = (const float*)d_in[5];
    const float* Wk = (const float*)d_in[6];
    const float* Wv = (const float*)d_in[7];
    const float* Wr = (const float*)d_in[8];
    const float* Wo = (const float*)d_in[9];

    const size_t MC = (size_t)Mq * Cq;

    __bf16* xk = (__bf16*)d_out;
    __bf16* xv = xk + MC;

    __bf16* xr   = (__bf16*)d_ws;
    __bf16* kbuf = xr + MC;
    __bf16* vbuf = kbuf + MC;
    __bf16* rbuf = vbuf + MC;
    __bf16* Wp   = rbuf + MC;
    __bf16* Wob  = Wp + 3 * 589824;

    prep_kernel<<<5760, 256, 0, stream>>>(x, mk, mv, mr, Wk, Wv, Wr, Wo,
                                          xk, xv, xr, Wp);

    // fused k|v|r GEMM: 256x256 8-phase-style, 432 blocks x 512 thr
    gemm_kvr8<<<432, 512, 0, stream>>>(xk, xv, xr, Wp, kbuf);

    scan_kernel<<<dim3(Cq / 128, Bq), dim3(64, SEG), 0, stream>>>(
        kbuf, vbuf, rbuf, td, tf);

    mfma_gemm_o<<<6 * 96, 256, 0, stream>>>(rbuf, Wob, (float*)d_out);
}